// Round 2
// baseline (373.719 us; speedup 1.0000x reference)
//
#include <hip/hip_runtime.h>

#define DT 0.03f
#define SEQ_LEN 30
#define D_STEER (0.4f * 0.03f)

#define KSTEP 10
#define ROUNDS 3
#define PAD 11   // float4 stride per row in LDS (10 + 1 pad)

__global__ __launch_bounds__(256) void ccdec_kernel(
    const float* __restrict__ z,
    const float* __restrict__ init_state,
    float* __restrict__ out,
    int B)
{
    __shared__ float4 lds[256 * PAD];   // 45056 B

    int tid = threadIdx.x;
    int b   = blockIdx.x * 256 + tid;
    bool valid = (b < B);
    int bb = valid ? b : (B - 1);       // clamp for safe loads

    // ---- loads ----
    float2 zv  = *reinterpret_cast<const float2*>(z + 2ull * (size_t)bb);
    const float* st = init_state + 6ull * (size_t)bb;
    float2 s01 = *reinterpret_cast<const float2*>(st + 0);
    float2 s23 = *reinterpret_cast<const float2*>(st + 2);
    float2 s45 = *reinterpret_cast<const float2*>(st + 4);

    float x   = s01.x;
    float y   = s01.y;
    float psi = s23.x;
    float v   = s23.y;
    float last_st = s45.y;   // init_state[:,5]

    // ---- steering / pedal preamble (mirror clip_by_tensor semantics) ----
    float steering = zv.y * 0.5f;
    float tmin = last_st - D_STEER;
    float tmax = last_st + D_STEER;
    float r = (steering > tmin) ? steering : ((steering < tmin) ? tmin : 0.0f);
    r = (r <= tmax) ? r : tmax;
    steering = fminf(fmaxf(r, -0.5f), 0.5f);

    float pedal = zv.x * 2.5f;
    float beta  = fminf(fmaxf(steering, -0.5f), 0.5f);
    float a_t   = fminf(fmaxf(pedal, -2.5f), 2.5f);
    float tan_beta = __tanf(beta);
    float dpsi_k   = tan_beta * (1.0f / 2.5f) * DT;
    float adt      = a_t * DT;

    // whole-block fast path only when the full 256-row tile is in range
    bool full_tile = ((blockIdx.x + 1) * 256 <= B);

    if (full_tile) {
        // tile base in float4 units: each row is 30 float4s
        float4* outp4 = reinterpret_cast<float4*>(out) + (size_t)blockIdx.x * 256 * 30;

        for (int round = 0; round < ROUNDS; ++round) {
            #pragma unroll
            for (int k = 0; k < KSTEP; ++k) {
                float v1 = fminf(fmaxf(v + adt, 0.0f), 10.0f);
                psi = v * dpsi_k + psi;          // uses OLD v
                float s, c;
                __sincosf(psi, &s, &c);
                x = v1 * c * DT + x;
                y = v1 * s * DT + y;
                v = v1;
                lds[tid * PAD + k] = make_float4(x, y, psi, v);
            }
            __syncthreads();

            int t0 = round * KSTEP;
            #pragma unroll
            for (int m = 0; m < KSTEP; ++m) {
                int f  = tid + m * 256;          // 0 .. 2559
                int rr = f / KSTEP;              // row within tile
                int jj = f - rr * KSTEP;         // step within round
                outp4[rr * 30 + t0 + jj] = lds[rr * PAD + jj];
            }
            __syncthreads();
        }
    } else {
        // remainder path: direct (uncoalesced) stores — correctness only
        if (valid) {
            float4* outp = reinterpret_cast<float4*>(out + 120ull * (size_t)b);
            #pragma unroll
            for (int t = 0; t < SEQ_LEN; ++t) {
                float v1 = fminf(fmaxf(v + adt, 0.0f), 10.0f);
                psi = v * dpsi_k + psi;
                float s, c;
                __sincosf(psi, &s, &c);
                x = v1 * c * DT + x;
                y = v1 * s * DT + y;
                v = v1;
                outp[t] = make_float4(x, y, psi, v);
            }
        }
    }
}

extern "C" void kernel_launch(void* const* d_in, const int* in_sizes, int n_in,
                              void* d_out, int out_size, void* d_ws, size_t ws_size,
                              hipStream_t stream)
{
    const float* z          = (const float*)d_in[0];   // (B, 2) f32
    const float* init_state = (const float*)d_in[1];   // (B, 6) f32
    float* out = (float*)d_out;                        // (B, 30, 4) f32

    int B = in_sizes[0] / 2;
    int blocks = (B + 255) / 256;
    ccdec_kernel<<<blocks, 256, 0, stream>>>(z, init_state, out, B);
}

// Round 3
// 188.302 us; speedup vs baseline: 1.9847x; 1.9847x over previous
//
#include <hip/hip_runtime.h>

#define DT 0.03f
#define SEQ_LEN 30
#define D_STEER (0.4f * 0.03f)

#define BT 64            // threads per block (one wave) == rows per block
#define PAD 31           // float4 stride per row in LDS (30 + 1 pad -> distinct start banks)

__global__ __launch_bounds__(64) void ccdec_kernel(
    const float* __restrict__ z,
    const float* __restrict__ init_state,
    float* __restrict__ out,
    int B)
{
    __shared__ float4 lds[BT * PAD];   // 64*31*16 = 31744 B -> 5 blocks/CU

    int tid = threadIdx.x;
    int b   = blockIdx.x * BT + tid;
    bool valid = (b < B);
    int bb = valid ? b : (B - 1);

    // ---- loads ----
    float2 zv  = *reinterpret_cast<const float2*>(z + 2ull * (size_t)bb);
    const float* st = init_state + 6ull * (size_t)bb;
    float2 s01 = *reinterpret_cast<const float2*>(st + 0);
    float2 s23 = *reinterpret_cast<const float2*>(st + 2);
    float2 s45 = *reinterpret_cast<const float2*>(st + 4);

    float x   = s01.x;
    float y   = s01.y;
    float psi = s23.x;
    float v   = s23.y;
    float last_st = s45.y;   // init_state[:,5]

    // ---- steering / pedal preamble (mirror clip_by_tensor semantics) ----
    float steering = zv.y * 0.5f;
    float tmin = last_st - D_STEER;
    float tmax = last_st + D_STEER;
    float r = (steering > tmin) ? steering : ((steering < tmin) ? tmin : 0.0f);
    r = (r <= tmax) ? r : tmax;
    steering = fminf(fmaxf(r, -0.5f), 0.5f);

    float pedal = zv.x * 2.5f;
    float beta  = fminf(fmaxf(steering, -0.5f), 0.5f);
    float a_t   = fminf(fmaxf(pedal, -2.5f), 2.5f);
    float tan_beta = __tanf(beta);
    float dpsi_k   = tan_beta * (1.0f / 2.5f) * DT;
    float adt      = a_t * DT;

    bool full_tile = ((blockIdx.x + 1) * BT <= B);

    if (full_tile) {
        // ---- compute all 30 steps into LDS (full rows) ----
        #pragma unroll
        for (int t = 0; t < SEQ_LEN; ++t) {
            float v1 = fminf(fmaxf(v + adt, 0.0f), 10.0f);
            psi = v * dpsi_k + psi;          // uses OLD v
            float s, c;
            __sincosf(psi, &s, &c);
            x = v1 * c * DT + x;
            y = v1 * s * DT + y;
            v = v1;
            lds[tid * PAD + t] = make_float4(x, y, psi, v);
        }
        __syncthreads();

        // ---- stream the tile out flat: every wave store = 16 full aligned lines ----
        // tile = BT rows x 30 float4 = 1920 float4 contiguous
        float4* outp4 = reinterpret_cast<float4*>(out) + (size_t)blockIdx.x * BT * SEQ_LEN;
        #pragma unroll
        for (int m = 0; m < SEQ_LEN; ++m) {
            int f  = tid + m * BT;           // 0 .. 1919, contiguous per wave
            int rr = f / SEQ_LEN;            // row within tile
            int jj = f - rr * SEQ_LEN;       // step
            outp4[f] = lds[rr * PAD + jj];
        }
    } else {
        if (valid) {
            float4* outp = reinterpret_cast<float4*>(out + 120ull * (size_t)b);
            #pragma unroll
            for (int t = 0; t < SEQ_LEN; ++t) {
                float v1 = fminf(fmaxf(v + adt, 0.0f), 10.0f);
                psi = v * dpsi_k + psi;
                float s, c;
                __sincosf(psi, &s, &c);
                x = v1 * c * DT + x;
                y = v1 * s * DT + y;
                v = v1;
                outp[t] = make_float4(x, y, psi, v);
            }
        }
    }
}

extern "C" void kernel_launch(void* const* d_in, const int* in_sizes, int n_in,
                              void* d_out, int out_size, void* d_ws, size_t ws_size,
                              hipStream_t stream)
{
    const float* z          = (const float*)d_in[0];   // (B, 2) f32
    const float* init_state = (const float*)d_in[1];   // (B, 6) f32
    float* out = (float*)d_out;                        // (B, 30, 4) f32

    int B = in_sizes[0] / 2;
    int blocks = (B + BT - 1) / BT;
    ccdec_kernel<<<blocks, BT, 0, stream>>>(z, init_state, out, B);
}